// Round 1
// baseline (183.318 us; speedup 1.0000x reference)
//
#include <hip/hip_runtime.h>
#include <hip/hip_bf16.h>

// GraphResBlock: B=8, N=256, F=64(N_IN), H=128(N_HID), E=16(EIN)
// out[b,i,:] = relu(mean_j relu(nef[b,j]+net[b,i]+e[b,i,j]@We+be  [j!=i]) @ W1 + b1) @ W2 + b2 + x[b,i]

#define BB 8
#define NN 256
#define FF 64
#define HH 128
#define EE 16

// ---------------- Kernel 1: ne_f = x@Wf+bf, ne_t = x@Wt+bt ----------------
// 16 rows per block, 128 threads (one per h), k-outer register accumulators.
__global__ __launch_bounds__(128) void k_node_emb(
    const float* __restrict__ x,
    const float* __restrict__ Wf, const float* __restrict__ bf,
    const float* __restrict__ Wt, const float* __restrict__ bt,
    float* __restrict__ nef, float* __restrict__ net)
{
    __shared__ float smxT[FF][20];   // transposed x tile, pad 20 (80B rows: float4-aligned, spread banks)
    const int tid = threadIdx.x;
    const int row0 = blockIdx.x * 16;

    // load 16 rows x 64 cols of x, store transposed
    #pragma unroll
    for (int v = 0; v < 8; ++v) {
        int idx = v * 128 + tid;         // 0..1023
        int r = idx >> 6, c = idx & 63;
        smxT[c][r] = x[(size_t)(row0 + r) * FF + c];
    }
    __syncthreads();

    const int h = tid;
    float accf[16], acct[16];
    const float bfv = bf[h], btv = bt[h];
    #pragma unroll
    for (int r = 0; r < 16; ++r) { accf[r] = bfv; acct[r] = btv; }

    for (int k = 0; k < FF; ++k) {
        const float wf = Wf[k * HH + h];
        const float wt = Wt[k * HH + h];
        const float4* xr = (const float4*)&smxT[k][0];
        #pragma unroll
        for (int q = 0; q < 4; ++q) {
            float4 xv = xr[q];
            accf[q*4+0] = fmaf(xv.x, wf, accf[q*4+0]);
            accf[q*4+1] = fmaf(xv.y, wf, accf[q*4+1]);
            accf[q*4+2] = fmaf(xv.z, wf, accf[q*4+2]);
            accf[q*4+3] = fmaf(xv.w, wf, accf[q*4+3]);
            acct[q*4+0] = fmaf(xv.x, wt, acct[q*4+0]);
            acct[q*4+1] = fmaf(xv.y, wt, acct[q*4+1]);
            acct[q*4+2] = fmaf(xv.z, wt, acct[q*4+2]);
            acct[q*4+3] = fmaf(xv.w, wt, acct[q*4+3]);
        }
    }
    #pragma unroll
    for (int r = 0; r < 16; ++r) {
        nef[(size_t)(row0 + r) * HH + h] = accf[r];
        net[(size_t)(row0 + r) * HH + h] = acct[r];
    }
}

// ---------------- Kernel 2: fused pair + relu + mean + MLP + residual ----------------
// One block per (b,i): row = b*N+i. 128 threads, one per h channel.
__global__ __launch_bounds__(128) void k_pair_mlp(
    const float* __restrict__ x, const float* __restrict__ e,
    const float* __restrict__ We, const float* __restrict__ be,
    const float* __restrict__ nef, const float* __restrict__ net,
    const float* __restrict__ W1, const float* __restrict__ b1,
    const float* __restrict__ W2, const float* __restrict__ b2,
    float* __restrict__ out)
{
    const int row = blockIdx.x;          // b*256 + i
    const int i = row & (NN - 1);
    const int h = threadIdx.x;

    // We column for this h in registers
    float we0  = We[ 0*HH+h], we1  = We[ 1*HH+h], we2  = We[ 2*HH+h], we3  = We[ 3*HH+h];
    float we4  = We[ 4*HH+h], we5  = We[ 5*HH+h], we6  = We[ 6*HH+h], we7  = We[ 7*HH+h];
    float we8  = We[ 8*HH+h], we9  = We[ 9*HH+h], we10 = We[10*HH+h], we11 = We[11*HH+h];
    float we12 = We[12*HH+h], we13 = We[13*HH+h], we14 = We[14*HH+h], we15 = We[15*HH+h];

    const float c = be[h] + net[(size_t)row * HH + h];

    // e[b,i,j,:] : block-uniform addresses -> scalar loads
    const float4* __restrict__ e4 = (const float4*)(e + (size_t)row * (NN * EE));
    const float* __restrict__ nefb = nef + (size_t)(row & ~(NN - 1)) * HH;

    float acc = 0.f;
    #pragma unroll 4
    for (int j = 0; j < NN; ++j) {
        const float4 q0 = e4[j*4+0];
        const float4 q1 = e4[j*4+1];
        const float4 q2 = e4[j*4+2];
        const float4 q3 = e4[j*4+3];
        float d = c + nefb[j * HH + h];
        d = fmaf(q0.x, we0,  d); d = fmaf(q0.y, we1,  d);
        d = fmaf(q0.z, we2,  d); d = fmaf(q0.w, we3,  d);
        d = fmaf(q1.x, we4,  d); d = fmaf(q1.y, we5,  d);
        d = fmaf(q1.z, we6,  d); d = fmaf(q1.w, we7,  d);
        d = fmaf(q2.x, we8,  d); d = fmaf(q2.y, we9,  d);
        d = fmaf(q2.z, we10, d); d = fmaf(q2.w, we11, d);
        d = fmaf(q3.x, we12, d); d = fmaf(q3.y, we13, d);
        d = fmaf(q3.z, we14, d); d = fmaf(q3.w, we15, d);
        d = fmaxf(d, 0.f);
        acc += (j != i) ? d : 0.f;
    }

    __shared__ float sm_ne[HH];
    __shared__ float sm_h[HH];
    sm_ne[h] = acc * (1.0f / (float)NN);
    __syncthreads();

    // h1 = relu(node_emb @ W1 + b1)
    float a1 = b1[h];
    for (int k = 0; k < HH; ++k) {
        a1 = fmaf(sm_ne[k], W1[k * HH + h], a1);
    }
    a1 = fmaxf(a1, 0.f);
    sm_h[h] = a1;
    __syncthreads();

    // out = h1 @ W2 + b2 + x
    if (h < FF) {
        float a2 = b2[h];
        for (int k = 0; k < HH; ++k) {
            a2 = fmaf(sm_h[k], W2[k * FF + h], a2);
        }
        out[(size_t)row * FF + h] = a2 + x[(size_t)row * FF + h];
    }
}

extern "C" void kernel_launch(void* const* d_in, const int* in_sizes, int n_in,
                              void* d_out, int out_size, void* d_ws, size_t ws_size,
                              hipStream_t stream) {
    const float* x  = (const float*)d_in[0];
    const float* e  = (const float*)d_in[1];
    const float* Wf = (const float*)d_in[2];
    const float* bf = (const float*)d_in[3];
    const float* Wt = (const float*)d_in[4];
    const float* bt = (const float*)d_in[5];
    const float* We = (const float*)d_in[6];
    const float* be = (const float*)d_in[7];
    const float* W1 = (const float*)d_in[8];
    const float* b1 = (const float*)d_in[9];
    const float* W2 = (const float*)d_in[10];
    const float* b2 = (const float*)d_in[11];
    float* out = (float*)d_out;

    float* nef = (float*)d_ws;                       // [B*N, H] = 1 MB
    float* net = nef + (size_t)BB * NN * HH;         // [B*N, H] = 1 MB

    k_node_emb<<<(BB * NN) / 16, 128, 0, stream>>>(x, Wf, bf, Wt, bt, nef, net);
    k_pair_mlp<<<BB * NN, 128, 0, stream>>>(x, e, We, be, nef, net, W1, b1, W2, b2, out);
}

// Round 3
// 129.209 us; speedup vs baseline: 1.4188x; 1.4188x over previous
//
#include <hip/hip_runtime.h>
#include <hip/hip_bf16.h>

// GraphResBlock: B=8, N=256, F=64(N_IN), H=128(N_HID), E=16(EIN)
// out[b,i,:] = relu(mean_j relu(nef[b,j]+net'[b,i]+e[b,i,j]@We)) @ W1 + b1) @ W2 + b2 + x[b,i]
// (all three biases bf,bt,be folded into net')

#define BB 8
#define NN 256
#define FF 64
#define HH 128
#define EE 16

typedef __attribute__((ext_vector_type(8))) short bf16x8;
typedef __attribute__((ext_vector_type(16))) float f32x16;

__device__ __forceinline__ short f2bf(float f) {
    union { float f; unsigned u; } v; v.f = f;
    unsigned r = v.u + 0x7FFFu + ((v.u >> 16) & 1u);   // round-to-nearest-even
    return (short)(r >> 16);
}
__device__ __forceinline__ float bf2f(short s) {
    union { unsigned u; float f; } v; v.u = ((unsigned)(unsigned short)s) << 16;
    return v.f;
}

// ---------------- Kernel 1: nef = x@Wf ; net' = x@Wt + (bf+bt+be) ----------------
// 4 rows per block, 128 threads (one per h). 512 blocks.
__global__ __launch_bounds__(128) void k_node_emb(
    const float* __restrict__ x,
    const float* __restrict__ Wf, const float* __restrict__ bf,
    const float* __restrict__ Wt, const float* __restrict__ bt,
    const float* __restrict__ be,
    float* __restrict__ nef, float* __restrict__ net)
{
    __shared__ float smx[4 * FF];
    const int tid = threadIdx.x;
    const int row0 = blockIdx.x * 4;

    smx[tid]       = x[(size_t)row0 * FF + tid];
    smx[tid + 128] = x[(size_t)row0 * FF + tid + 128];
    __syncthreads();

    const int h = tid;
    const float bsum = bf[h] + bt[h] + be[h];
    float af0 = 0.f, af1 = 0.f, af2 = 0.f, af3 = 0.f;
    float at0 = bsum, at1 = bsum, at2 = bsum, at3 = bsum;

    #pragma unroll 8
    for (int k = 0; k < FF; ++k) {
        const float wf = Wf[k * HH + h];
        const float wt = Wt[k * HH + h];
        const float x0 = smx[k], x1 = smx[FF + k], x2 = smx[2 * FF + k], x3 = smx[3 * FF + k];
        af0 = fmaf(x0, wf, af0); af1 = fmaf(x1, wf, af1);
        af2 = fmaf(x2, wf, af2); af3 = fmaf(x3, wf, af3);
        at0 = fmaf(x0, wt, at0); at1 = fmaf(x1, wt, at1);
        at2 = fmaf(x2, wt, at2); at3 = fmaf(x3, wt, at3);
    }
    nef[(size_t)(row0 + 0) * HH + h] = af0;
    nef[(size_t)(row0 + 1) * HH + h] = af1;
    nef[(size_t)(row0 + 2) * HH + h] = af2;
    nef[(size_t)(row0 + 3) * HH + h] = af3;
    net[(size_t)(row0 + 0) * HH + h] = at0;
    net[(size_t)(row0 + 1) * HH + h] = at1;
    net[(size_t)(row0 + 2) * HH + h] = at2;
    net[(size_t)(row0 + 3) * HH + h] = at3;
}

// ---------------- Kernel 2: bf16-MFMA pair + relu + mean + MLP + residual ----------------
// One block per (b,i), 256 threads = 4 waves. Each wave: 2 j-tiles (32 j) x 4 h-tiles (32 h).
__global__ __launch_bounds__(256) void k_pair_mfma(
    const float* __restrict__ x, const float* __restrict__ e,
    const float* __restrict__ We,
    const float* __restrict__ nef, const float* __restrict__ net,
    const float* __restrict__ W1, const float* __restrict__ b1,
    const float* __restrict__ W2, const float* __restrict__ b2,
    float* __restrict__ out)
{
    const int row  = blockIdx.x;            // b*256 + i
    const int b    = row >> 8;
    const int i    = row & (NN - 1);
    const int tid  = threadIdx.x;
    const int wave = tid >> 6;
    const int lane = tid & 63;
    const int c    = lane & 31;             // col within 32-tile (h offset / j offset)
    const int half = lane >> 5;             // k-half selector

    __shared__ float smred[4][HH];
    __shared__ float sm_ne[HH];
    __shared__ float sm_h1[HH];

    // ---- B fragments: We columns, bf16. Our k-mapping: k = 8*half + elem
    // (any bijection is fine as long as A and B use the same one).
    bf16x8 bfrag[4];
    #pragma unroll
    for (int ht = 0; ht < 4; ++ht) {
        bf16x8 t;
        #pragma unroll
        for (int el = 0; el < 8; ++el) {
            const int k = 8 * half + el;
            t[el] = f2bf(We[k * HH + ht * 32 + c]);
        }
        bfrag[ht] = t;
    }

    float netv[4];
    #pragma unroll
    for (int ht = 0; ht < 4; ++ht) netv[ht] = net[(size_t)row * HH + ht * 32 + c];

    const float* __restrict__ eRow = e + (size_t)row * (NN * EE);
    const float* __restrict__ nefb = nef + (size_t)b * (NN * HH);

    float acc[4] = {0.f, 0.f, 0.f, 0.f};

    #pragma unroll
    for (int q = 0; q < 2; ++q) {
        const int jt = wave * 2 + q;        // j-tile index 0..7
        const int j  = jt * 32 + c;         // A row = lane&31
        // A fragment: e[b,i,j, 8*half .. 8*half+7] as bf16 (same k-mapping as B)
        const float4* ap = (const float4*)(eRow + (size_t)j * EE + 8 * half);
        const float4 p0 = ap[0];
        const float4 p1 = ap[1];
        bf16x8 afrag;
        afrag[0] = f2bf(p0.x); afrag[1] = f2bf(p0.y);
        afrag[2] = f2bf(p0.z); afrag[3] = f2bf(p0.w);
        afrag[4] = f2bf(p1.x); afrag[5] = f2bf(p1.y);
        afrag[6] = f2bf(p1.z); afrag[7] = f2bf(p1.w);

        #pragma unroll
        for (int ht = 0; ht < 4; ++ht) {
            f32x16 d = {0.f,0.f,0.f,0.f,0.f,0.f,0.f,0.f,0.f,0.f,0.f,0.f,0.f,0.f,0.f,0.f};
            d = __builtin_amdgcn_mfma_f32_32x32x16_bf16(afrag, bfrag[ht], d, 0, 0, 0);
            // D layout (verified m74/m101): col = lane&31, row = (reg&3)+8*(reg>>2)+4*(lane>>5)
            #pragma unroll
            for (int r = 0; r < 16; ++r) {
                const int rowj = (r & 3) + 8 * (r >> 2) + 4 * half;
                const float v = d[r] + netv[ht]
                              + nefb[(size_t)(jt * 32 + rowj) * HH + ht * 32 + c];
                acc[ht] += fmaxf(v, 0.f);
            }
        }
    }

    // reduce the two lane-halves (they hold disjoint j-rows of the same h column)
    #pragma unroll
    for (int ht = 0; ht < 4; ++ht) acc[ht] += __shfl_xor(acc[ht], 32);
    if (lane < 32) {
        #pragma unroll
        for (int ht = 0; ht < 4; ++ht) smred[wave][ht * 32 + c] = acc[ht];
    }
    __syncthreads();

    // ---- combine waves, subtract bf16-rounded diagonal, mean ----
    if (tid < HH) {
        const int h = tid;
        float s = smred[0][h] + smred[1][h] + smred[2][h] + smred[3][h];
        float dd = nefb[(size_t)i * HH + h] + net[(size_t)row * HH + h];
        const float* ed = eRow + (size_t)i * EE;
        #pragma unroll
        for (int k = 0; k < EE; ++k) {
            dd = fmaf(bf2f(f2bf(ed[k])), bf2f(f2bf(We[k * HH + h])), dd);
        }
        s -= fmaxf(dd, 0.f);
        sm_ne[h] = s * (1.0f / (float)NN);
    }
    __syncthreads();

    // ---- h1 = relu(node_emb @ W1 + b1) ----
    if (tid < HH) {
        const int h = tid;
        float a1 = b1[h];
        #pragma unroll 4
        for (int k = 0; k < HH; ++k) a1 = fmaf(sm_ne[k], W1[k * HH + h], a1);
        sm_h1[h] = fmaxf(a1, 0.f);
    }
    __syncthreads();

    // ---- out = h1 @ W2 + b2 + x ----
    if (tid < FF) {
        const int h = tid;
        float a2 = b2[h] + x[(size_t)row * FF + h];
        #pragma unroll 4
        for (int k = 0; k < HH; ++k) a2 = fmaf(sm_h1[k], W2[k * FF + h], a2);
        out[(size_t)row * FF + h] = a2;
    }
}

extern "C" void kernel_launch(void* const* d_in, const int* in_sizes, int n_in,
                              void* d_out, int out_size, void* d_ws, size_t ws_size,
                              hipStream_t stream) {
    (void)in_sizes; (void)n_in; (void)out_size; (void)ws_size;
    const float* x  = (const float*)d_in[0];
    const float* e  = (const float*)d_in[1];
    const float* Wf = (const float*)d_in[2];
    const float* bf = (const float*)d_in[3];
    const float* Wt = (const float*)d_in[4];
    const float* bt = (const float*)d_in[5];
    const float* We = (const float*)d_in[6];
    const float* be = (const float*)d_in[7];
    const float* W1 = (const float*)d_in[8];
    const float* b1 = (const float*)d_in[9];
    const float* W2 = (const float*)d_in[10];
    const float* b2 = (const float*)d_in[11];
    float* out = (float*)d_out;

    float* nef = (float*)d_ws;                       // [B*N, H] = 1 MB
    float* net = nef + (size_t)BB * NN * HH;         // [B*N, H] = 1 MB

    k_node_emb<<<(BB * NN) / 4, 128, 0, stream>>>(x, Wf, bf, Wt, bt, be, nef, net);
    k_pair_mfma<<<BB * NN, 256, 0, stream>>>(x, e, We, nef, net, W1, b1, W2, b2, out);
}